// Round 6
// baseline (1527.919 us; speedup 1.0000x reference)
//
#include <hip/hip_runtime.h>

// Problem constants (fixed by the reference)
constexpr int Mdim = 32;      // b*c
constexpr int Kdim = 16384;   // rows*cols
constexpr int Ndim = 16384;   // h*w

constexpr int TPB = 256;

// GEMM tiling
constexpr int NB      = 128;            // n-columns per block
constexpr int NTILES  = Ndim / NB;      // 128
constexpr int KT      = 4;              // split-K chunks -> grid 512 = 2 blocks/CU
constexpr int KC      = Kdim / KT;      // 4096 k per block
constexpr int KB      = 64;             // k-rows per LDS tile
constexpr int NCHUNK  = KC / KB;        // 64

typedef short bf16x8 __attribute__((ext_vector_type(8)));   // 8 bf16 = 16 B
typedef float f32x4  __attribute__((ext_vector_type(4)));

// fp32 -> bf16 RNE (proven R5: absmax 0.0039)
__device__ __forceinline__ short f32_to_bf16(float f) {
    union { float f; unsigned u; } c; c.f = f;
    unsigned u = c.u;
    u += 0x7fffu + ((u >> 16) & 1u);
    return (short)(u >> 16);
}

// LDS barrier that does NOT drain vmcnt: in-flight global prefetches survive.
#define LDS_BARRIER() asm volatile("s_waitcnt lgkmcnt(0)\n\ts_barrier" ::: "memory")

// 16B-unit XOR swizzle: conflict-free (2-way) for both transposed writes and
// fragment reads. unit u in [0,8), column n in [0,128).
__device__ __forceinline__ int lds_addr(int n, int u) {   // in shorts
    const int s = (n ^ (n >> 3)) & 7;
    return n * 64 + ((u ^ s) & 7) * 8;
}

// ---------------------------------------------------------------------------
// Phase 0: A-fragments of x, MFMA 16x16x32 layout, bf16 (unchanged from R5).
//   A[m = mt*16 + (lane&15)][k = kc*32 + (lane>>4)*8 + j], scaled 1/128.
// ---------------------------------------------------------------------------
__global__ __launch_bounds__(TPB)
void build_xa(const float* __restrict__ image, short* __restrict__ xa) {
    const int g    = blockIdx.x * TPB + threadIdx.x;
    const int lane = g & 63;
    const int frag = g >> 6;
    const int mt   = frag & 1;
    const int kc   = frag >> 1;
    const int m    = mt * 16 + (lane & 15);
    const int k    = kc * 32 + (lane >> 4) * 8;
    const float* src = image + (size_t)m * Kdim + k;

    bf16x8 o;
    #pragma unroll
    for (int j = 0; j < 8; ++j)
        o[j] = f32_to_bf16(fmaxf(src[j], 0.0f) * (1.0f / 128.0f));
    reinterpret_cast<bf16x8*>(xa)[g] = o;
}

// ---------------------------------------------------------------------------
// Phase 1: split-K MFMA GEMM, transposed-LDS + depth-2 prefetch pipeline.
// ---------------------------------------------------------------------------
__global__ __launch_bounds__(TPB, 2)
void ht_gemm(const short* __restrict__ xa,    // A-fragments (bf16)
             const float* __restrict__ vote,  // (K, N) fp32
             float* __restrict__ parts)       // (KT, 32, N) fp32 partials
{
    __shared__ __align__(16) short lds[2][NB * KB];   // 2 x 16 KB

    const int tid    = threadIdx.x;
    const int lane   = tid & 63;
    const int w      = tid >> 6;
    const int ntile  = blockIdx.x & (NTILES - 1);
    const int kchunk = blockIdx.x >> 7;
    const int k0     = kchunk * KC;
    const int n0     = ntile * NB;

    // staging: thread owns 8 consecutive k-rows x 4 consecutive n-cols
    const int s_k  = tid >> 5;                // 0..7  (k-row octet)
    const int s_c4 = tid & 31;                // 0..31 (float4 column group)

    // B-fragment lane decomposition
    const int bq = lane >> 4;                 // k-quad
    const int bn = lane & 15;                 // n within 16

    f32x4 acc[2][2];                          // [mt][cl]
    #pragma unroll
    for (int a = 0; a < 2; ++a)
        #pragma unroll
        for (int b = 0; b < 2; ++b) { f32x4 z = {0.f, 0.f, 0.f, 0.f}; acc[a][b] = z; }

    float4 tmp[2][8];                         // depth-2 in-flight V (64 VGPRs)

    auto load_tile = [&](int slot, int ch) {
        const float* s = vote + ((size_t)(k0 + ch * KB + s_k * 8)) * Ndim + n0 + s_c4 * 4;
        #pragma unroll
        for (int i = 0; i < 8; ++i)
            tmp[slot][i] = *reinterpret_cast<const float4*>(s + (size_t)i * Ndim);
    };
    auto write_tile = [&](int buf, int slot) {
        #pragma unroll
        for (int c = 0; c < 4; ++c) {
            const int n = s_c4 * 4 + c;
            bf16x8 v;
            #pragma unroll
            for (int i = 0; i < 8; ++i) {
                const float4 t = tmp[slot][i];
                v[i] = f32_to_bf16(c == 0 ? t.x : c == 1 ? t.y : c == 2 ? t.z : t.w);
            }
            *reinterpret_cast<bf16x8*>(&lds[buf][lds_addr(n, s_k)]) = v;  // ds_write_b128
        }
    };
    auto compute = [&](int buf, int ch) {
        #pragma unroll
        for (int rs = 0; rs < 2; ++rs) {                   // two k32 slabs
            const int kcg = (k0 >> 5) + ch * 2 + rs;
            const bf16x8 a0 = *reinterpret_cast<const bf16x8*>(
                xa + ((size_t)(kcg * 2 + 0) * 64 + lane) * 8);
            const bf16x8 a1 = *reinterpret_cast<const bf16x8*>(
                xa + ((size_t)(kcg * 2 + 1) * 64 + lane) * 8);
            #pragma unroll
            for (int cl = 0; cl < 2; ++cl) {
                const int n = w * 32 + cl * 16 + bn;
                const bf16x8 bf = *reinterpret_cast<const bf16x8*>(
                    &lds[buf][lds_addr(n, rs * 4 + bq)]);  // ds_read_b128
                acc[0][cl] = __builtin_amdgcn_mfma_f32_16x16x32_bf16(a0, bf, acc[0][cl], 0, 0, 0);
                acc[1][cl] = __builtin_amdgcn_mfma_f32_16x16x32_bf16(a1, bf, acc[1][cl], 0, 0, 0);
            }
        }
    };

    load_tile(0, 0);
    load_tile(1, 1);
    for (int ch = 0; ch < NCHUNK; ++ch) {
        const int slot = ch & 1;
        write_tile(slot, slot);               // waits (vmcnt) only on ch's loads
        if (ch + 2 < NCHUNK) load_tile(slot, ch + 2);   // stays in flight across barrier
        LDS_BARRIER();                        // lgkmcnt(0) + s_barrier, vmcnt untouched
        compute(slot, ch);
    }

    // Epilogue: C/D col = bn, row = bq*4 + r  [R5-verified]
    float* pb = parts + (size_t)kchunk * ((size_t)Mdim * Ndim);
    #pragma unroll
    for (int mt = 0; mt < 2; ++mt)
        #pragma unroll
        for (int cl = 0; cl < 2; ++cl)
            #pragma unroll
            for (int r = 0; r < 4; ++r) {
                const int row = mt * 16 + bq * 4 + r;
                const int col = n0 + w * 32 + cl * 16 + bn;
                pb[(size_t)row * Ndim + col] = acc[mt][cl][r];
            }
}

// ---------------------------------------------------------------------------
// Phase 2: out[i] = sum_c parts[c][i]
// ---------------------------------------------------------------------------
__global__ __launch_bounds__(TPB)
void ht_reduce(const float* __restrict__ parts, float* __restrict__ out, int nchunks) {
    const size_t i4 = (size_t)blockIdx.x * TPB + threadIdx.x;
    const float4* p = reinterpret_cast<const float4*>(parts) + i4;
    float4 s = make_float4(0.f, 0.f, 0.f, 0.f);
    constexpr size_t stride4 = (size_t)Mdim * Ndim / 4;
    for (int c = 0; c < nchunks; ++c) {
        const float4 v = p[(size_t)c * stride4];
        s.x += v.x; s.y += v.y; s.z += v.z; s.w += v.w;
    }
    reinterpret_cast<float4*>(out)[i4] = s;
}

// ---------------------------------------------------------------------------
// Fallback (tiny ws): fp32 atomic version — correct, slower.
// ---------------------------------------------------------------------------
__global__ __launch_bounds__(TPB)
void ht_gemm_atomic(const float* __restrict__ image, const float* __restrict__ vote,
                    float* __restrict__ out) {
    __shared__ float xsh[256 * Mdim];
    const int tid = threadIdx.x;
    const int ntile = blockIdx.x % 16;
    const int k0 = (blockIdx.x / 16) * 256;
    const int nn0 = ntile * 1024 + tid * 4;
    for (int idx = tid; idx < 256 * Mdim; idx += TPB) {
        const int kk = idx >> 5, m = idx & 31;
        xsh[idx] = fmaxf(image[(size_t)m * Kdim + (k0 + kk)], 0.0f) * (1.0f / 128.0f);
    }
    __syncthreads();
    float4 acc[Mdim];
    #pragma unroll
    for (int m = 0; m < Mdim; ++m) acc[m] = make_float4(0.f, 0.f, 0.f, 0.f);
    const float* vptr = vote + (size_t)k0 * Ndim + nn0;
    for (int kk = 0; kk < 256; ++kk) {
        const float4 v = *reinterpret_cast<const float4*>(vptr);
        vptr += Ndim;
        #pragma unroll
        for (int m = 0; m < Mdim; ++m) {
            const float s = xsh[kk * Mdim + m];
            acc[m].x = fmaf(s, v.x, acc[m].x); acc[m].y = fmaf(s, v.y, acc[m].y);
            acc[m].z = fmaf(s, v.z, acc[m].z); acc[m].w = fmaf(s, v.w, acc[m].w);
        }
    }
    #pragma unroll
    for (int m = 0; m < Mdim; ++m) {
        float* o = out + (size_t)m * Ndim + nn0;
        unsafeAtomicAdd(o + 0, acc[m].x); unsafeAtomicAdd(o + 1, acc[m].y);
        unsafeAtomicAdd(o + 2, acc[m].z); unsafeAtomicAdd(o + 3, acc[m].w);
    }
}

extern "C" void kernel_launch(void* const* d_in, const int* in_sizes, int n_in,
                              void* d_out, int out_size, void* d_ws, size_t ws_size,
                              hipStream_t stream) {
    const float* image = (const float*)d_in[0];   // (32, 16384)
    const float* vote  = (const float*)d_in[1];   // (16384, 16384)
    float* out = (float*)d_out;                   // (32, 16384)

    const size_t xa_bytes    = (size_t)(Kdim / 32) * 2 * 64 * 8 * sizeof(short); // 1 MB
    const size_t chunk_bytes = (size_t)Mdim * Ndim * sizeof(float);              // 2 MB

    if (xa_bytes + (size_t)KT * chunk_bytes > ws_size) {
        (void)hipMemsetAsync(out, 0, (size_t)out_size * sizeof(float), stream);
        ht_gemm_atomic<<<dim3(16 * 64), TPB, 0, stream>>>(image, vote, out);
        return;
    }

    short* xa    = (short*)d_ws;
    float* parts = (float*)((char*)d_ws + xa_bytes);

    build_xa<<<dim3((Kdim / 32) * 2 * 64 / TPB), TPB, 0, stream>>>(image, xa);
    ht_gemm<<<dim3(NTILES * KT), TPB, 0, stream>>>(xa, vote, parts);
    ht_reduce<<<dim3((Mdim * Ndim) / (4 * TPB)), TPB, 0, stream>>>(parts, out, KT);
}

// Round 7
// 1328.014 us; speedup vs baseline: 1.1505x; 1.1505x over previous
//
#include <hip/hip_runtime.h>

// Problem constants (fixed by the reference)
constexpr int Mdim = 32;      // b*c
constexpr int Kdim = 16384;   // rows*cols
constexpr int Ndim = 16384;   // h*w

constexpr int TPB = 256;

// Tiling: one wave owns 32 n-cols x (Kdim/KT) k. No LDS, no barriers.
constexpr int KT     = 8;               // split-K chunks
constexpr int KC     = Kdim / KT;       // 2048 k per wave
constexpr int SLABS  = KC / 32;         // 64 k32-slabs per wave
constexpr int NT32   = Ndim / 32;       // 512 n-tiles
constexpr int NWAVES = NT32 * KT;       // 4096 waves
constexpr int NBLK   = NWAVES / 4;      // 1024 blocks (4 waves each)

typedef short bf16x8 __attribute__((ext_vector_type(8)));   // 8 bf16 = 16 B
typedef float f32x4  __attribute__((ext_vector_type(4)));

// fp32 -> bf16 RNE (proven R5: absmax 0.0039)
__device__ __forceinline__ short f32_to_bf16(float f) {
    union { float f; unsigned u; } c; c.f = f;
    unsigned u = c.u;
    u += 0x7fffu + ((u >> 16) & 1u);
    return (short)(u >> 16);
}

// ---------------------------------------------------------------------------
// Phase 0: A-fragments of x, MFMA 16x16x32 layout, bf16 (unchanged from R5).
//   A[m = mt*16 + (lane&15)][k = kc*32 + (lane>>4)*8 + j], scaled 1/128.
//   xa[((kc*2+mt)*64 + lane)*8 + j]
// ---------------------------------------------------------------------------
__global__ __launch_bounds__(TPB)
void build_xa(const float* __restrict__ image, short* __restrict__ xa) {
    const int g    = blockIdx.x * TPB + threadIdx.x;
    const int lane = g & 63;
    const int frag = g >> 6;
    const int mt   = frag & 1;
    const int kc   = frag >> 1;
    const int m    = mt * 16 + (lane & 15);
    const int k    = kc * 32 + (lane >> 4) * 8;
    const float* src = image + (size_t)m * Kdim + k;

    bf16x8 o;
    #pragma unroll
    for (int j = 0; j < 8; ++j)
        o[j] = f32_to_bf16(fmaxf(src[j], 0.0f) * (1.0f / 128.0f));
    reinterpret_cast<bf16x8*>(xa)[g] = o;
}

// ---------------------------------------------------------------------------
// Phase 1: barrier-free split-K MFMA GEMM.
// Wave wv: n-tile nt = wv & 511 (cols nt*32..+32), k-chunk = wv >> 9.
// B-fragments loaded straight from global V (dword/lane: 4 rows x 64 B
// segments per instr; cl0+cl1 cover full 128-B lines), cvt'd to bf16 in
// VALU, fed to MFMA. Depth-2 slab pipeline on vmcnt only — no syncthreads.
// ---------------------------------------------------------------------------
__global__ __launch_bounds__(TPB, 4)
void ht_gemm(const short* __restrict__ xa,    // A-fragments (bf16)
             const float* __restrict__ vote,  // (K, N) fp32
             float* __restrict__ parts)       // (KT, 32, N) fp32 partials
{
    const int tid  = threadIdx.x;
    const int lane = tid & 63;
    const int w    = tid >> 6;
    const int wv   = blockIdx.x * 4 + w;      // 0..4095
    const int nt   = wv & (NT32 - 1);         // n-tile
    const int kch  = wv >> 9;                 // k-chunk
    const int k0   = kch * KC;

    const int bq   = lane >> 4;               // k-quad
    const int bn   = lane & 15;               // n within 16
    const int ncol = nt * 32 + bn;

    f32x4 acc[2][2];                          // [mt][cl]
    #pragma unroll
    for (int a = 0; a < 2; ++a)
        #pragma unroll
        for (int b = 0; b < 2; ++b) { f32x4 z = {0.f, 0.f, 0.f, 0.f}; acc[a][b] = z; }

    const float* vbase = vote + (size_t)(k0 + bq * 8) * Ndim + ncol;
    const short* abase = xa + ((size_t)(k0 >> 5) * 128 + lane) * 8;

    float b0[16], b1[16];                     // depth-2 V slabs (32 VGPRs)

    auto load_b = [&](float* d, int s) {
        const float* p = vbase + (size_t)s * 32 * Ndim;
        #pragma unroll
        for (int j = 0; j < 8; ++j) {
            d[j]     = p[(size_t)j * Ndim];        // cl=0: cols ncol
            d[8 + j] = p[(size_t)j * Ndim + 16];   // cl=1: cols ncol+16
        }
    };
    auto compute = [&](const float* b, int s) {
        const bf16x8 a0 = *reinterpret_cast<const bf16x8*>(abase + (size_t)s * 1024);
        const bf16x8 a1 = *reinterpret_cast<const bf16x8*>(abase + (size_t)s * 1024 + 512);
        bf16x8 f0, f1;
        #pragma unroll
        for (int j = 0; j < 8; ++j) {
            f0[j] = f32_to_bf16(b[j]);
            f1[j] = f32_to_bf16(b[8 + j]);
        }
        acc[0][0] = __builtin_amdgcn_mfma_f32_16x16x32_bf16(a0, f0, acc[0][0], 0, 0, 0);
        acc[1][0] = __builtin_amdgcn_mfma_f32_16x16x32_bf16(a1, f0, acc[1][0], 0, 0, 0);
        acc[0][1] = __builtin_amdgcn_mfma_f32_16x16x32_bf16(a0, f1, acc[0][1], 0, 0, 0);
        acc[1][1] = __builtin_amdgcn_mfma_f32_16x16x32_bf16(a1, f1, acc[1][1], 0, 0, 0);
    };

    load_b(b0, 0);
    for (int s = 0; s < SLABS; s += 2) {
        load_b(b1, s + 1);                    // in flight during compute(b0)
        compute(b0, s);
        if (s + 2 < SLABS) load_b(b0, s + 2); // in flight during compute(b1)
        compute(b1, s + 1);
    }

    // Epilogue: C/D col = bn, row = bq*4 + r  [R5-verified]
    float* pb = parts + (size_t)kch * ((size_t)Mdim * Ndim);
    #pragma unroll
    for (int mt = 0; mt < 2; ++mt)
        #pragma unroll
        for (int cl = 0; cl < 2; ++cl)
            #pragma unroll
            for (int r = 0; r < 4; ++r) {
                const int row = mt * 16 + bq * 4 + r;
                const int col = nt * 32 + cl * 16 + bn;
                pb[(size_t)row * Ndim + col] = acc[mt][cl][r];
            }
}

// ---------------------------------------------------------------------------
// Phase 2: out[i] = sum_c parts[c][i]
// ---------------------------------------------------------------------------
__global__ __launch_bounds__(TPB)
void ht_reduce(const float* __restrict__ parts, float* __restrict__ out, int nchunks) {
    const size_t i4 = (size_t)blockIdx.x * TPB + threadIdx.x;
    const float4* p = reinterpret_cast<const float4*>(parts) + i4;
    float4 s = make_float4(0.f, 0.f, 0.f, 0.f);
    constexpr size_t stride4 = (size_t)Mdim * Ndim / 4;
    for (int c = 0; c < nchunks; ++c) {
        const float4 v = p[(size_t)c * stride4];
        s.x += v.x; s.y += v.y; s.z += v.z; s.w += v.w;
    }
    reinterpret_cast<float4*>(out)[i4] = s;
}

// ---------------------------------------------------------------------------
// Fallback (tiny ws): fp32 atomic version — correct, slower.
// ---------------------------------------------------------------------------
__global__ __launch_bounds__(TPB)
void ht_gemm_atomic(const float* __restrict__ image, const float* __restrict__ vote,
                    float* __restrict__ out) {
    __shared__ float xsh[256 * Mdim];
    const int tid = threadIdx.x;
    const int ntile = blockIdx.x % 16;
    const int k0 = (blockIdx.x / 16) * 256;
    const int nn0 = ntile * 1024 + tid * 4;
    for (int idx = tid; idx < 256 * Mdim; idx += TPB) {
        const int kk = idx >> 5, m = idx & 31;
        xsh[idx] = fmaxf(image[(size_t)m * Kdim + (k0 + kk)], 0.0f) * (1.0f / 128.0f);
    }
    __syncthreads();
    float4 acc[Mdim];
    #pragma unroll
    for (int m = 0; m < Mdim; ++m) acc[m] = make_float4(0.f, 0.f, 0.f, 0.f);
    const float* vptr = vote + (size_t)k0 * Ndim + nn0;
    for (int kk = 0; kk < 256; ++kk) {
        const float4 v = *reinterpret_cast<const float4*>(vptr);
        vptr += Ndim;
        #pragma unroll
        for (int m = 0; m < Mdim; ++m) {
            const float s = xsh[kk * Mdim + m];
            acc[m].x = fmaf(s, v.x, acc[m].x); acc[m].y = fmaf(s, v.y, acc[m].y);
            acc[m].z = fmaf(s, v.z, acc[m].z); acc[m].w = fmaf(s, v.w, acc[m].w);
        }
    }
    #pragma unroll
    for (int m = 0; m < Mdim; ++m) {
        float* o = out + (size_t)m * Ndim + nn0;
        unsafeAtomicAdd(o + 0, acc[m].x); unsafeAtomicAdd(o + 1, acc[m].y);
        unsafeAtomicAdd(o + 2, acc[m].z); unsafeAtomicAdd(o + 3, acc[m].w);
    }
}

extern "C" void kernel_launch(void* const* d_in, const int* in_sizes, int n_in,
                              void* d_out, int out_size, void* d_ws, size_t ws_size,
                              hipStream_t stream) {
    const float* image = (const float*)d_in[0];   // (32, 16384)
    const float* vote  = (const float*)d_in[1];   // (16384, 16384)
    float* out = (float*)d_out;                   // (32, 16384)

    const size_t xa_bytes    = (size_t)(Kdim / 32) * 2 * 64 * 8 * sizeof(short); // 1 MB
    const size_t chunk_bytes = (size_t)Mdim * Ndim * sizeof(float);              // 2 MB

    if (xa_bytes + (size_t)KT * chunk_bytes > ws_size) {
        (void)hipMemsetAsync(out, 0, (size_t)out_size * sizeof(float), stream);
        ht_gemm_atomic<<<dim3(16 * 64), TPB, 0, stream>>>(image, vote, out);
        return;
    }

    short* xa    = (short*)d_ws;
    float* parts = (float*)((char*)d_ws + xa_bytes);

    build_xa<<<dim3((Kdim / 32) * 2 * 64 / TPB), TPB, 0, stream>>>(image, xa);
    ht_gemm<<<dim3(NBLK), TPB, 0, stream>>>(xa, vote, parts);
    ht_reduce<<<dim3((Mdim * Ndim) / (4 * TPB)), TPB, 0, stream>>>(parts, out, KT);
}